// Round 1
// baseline (740.512 us; speedup 1.0000x reference)
//
#include <hip/hip_runtime.h>
#include <cstdint>
#include <cstddef>

#define N_ 32
#define C_ 256
#define H_ 56
#define W_ 56
#define PWORDS 4   // 256 channels / 64 bits

// workspace layout (bytes)
static constexpr size_t PX_ELEMS = (size_t)N_ * H_ * W_ * PWORDS;     // 401408 u64
static constexpr size_t PX_BYTES = PX_ELEMS * 8;                      // 3,211,264
static constexpr size_t PWB_OFF  = PX_BYTES;                          // packed weights
static constexpr size_t PW_ELEMS = (size_t)C_ * 9 * PWORDS;           // 9216 u64
static constexpr size_t T_OFF    = PWB_OFF + PW_ELEMS * 8;
static constexpr size_t S_OFF    = T_OFF + (size_t)C_ * 9 * 4;

// ---------------- kernel 1: pack sign bits of x ----------------
// px layout: [n][h][w][word]  (word = group of 64 input channels)
__global__ __launch_bounds__(256) void pack_x_kernel(const float* __restrict__ x,
                                                     unsigned long long* __restrict__ px) {
    int idx = blockIdx.x * 256 + threadIdx.x;           // exactly 32*4*56*56 threads
    int w = idx % W_;
    int t = idx / W_;
    int h = t % H_;
    int t2 = t / H_;
    int word = t2 & 3;
    int n = t2 >> 2;
    const float* xp = x + ((size_t)(n * C_ + word * 64)) * (H_ * W_) + h * W_ + w;
    unsigned int lo = 0, hi = 0;
#pragma unroll
    for (int b = 0; b < 32; ++b)
        lo |= (xp[(size_t)b * (H_ * W_)] > 0.0f ? 1u : 0u) << b;
#pragma unroll
    for (int b = 0; b < 32; ++b)
        hi |= (xp[(size_t)(b + 32) * (H_ * W_)] > 0.0f ? 1u : 0u) << b;
    px[((size_t)(n * H_ + h) * W_ + w) * PWORDS + word] =
        ((unsigned long long)hi << 32) | (unsigned long long)lo;
}

// ---------------- kernel 2: binarize weights ----------------
// pw layout: [o][tap][word], tap = kh*3+kw; Tg[o][tap] = 256 - 2*popc256(bits)
__global__ __launch_bounds__(256) void pack_w_kernel(const float* __restrict__ wt,
                                                     unsigned long long* __restrict__ pw,
                                                     int* __restrict__ Tg,
                                                     float* __restrict__ scaleg) {
    __shared__ double red[256];
    __shared__ unsigned long long wb[36];
    int o = blockIdx.x, tid = threadIdx.x;
    const float* wo = wt + (size_t)o * 2304;

    double s = 0;
    for (int j = tid; j < 2304; j += 256) s += (double)wo[j];
    red[tid] = s;
    __syncthreads();
    for (int k = 128; k > 0; k >>= 1) {
        if (tid < k) red[tid] += red[tid + k];
        __syncthreads();
    }
    double mean = red[0] / 2304.0;
    __syncthreads();

    double s2 = 0;
    for (int j = tid; j < 2304; j += 256) s2 += fabs((double)wo[j] - mean);
    red[tid] = s2;
    __syncthreads();
    for (int k = 128; k > 0; k >>= 1) {
        if (tid < k) red[tid] += red[tid + k];
        __syncthreads();
    }
    float scale = (float)(red[0] / 2304.0);

    if (tid < 36) {
        int tap = tid >> 2, word = tid & 3;
        unsigned long long bits = 0;
        for (int b = 0; b < 64; ++b) {
            int i = word * 64 + b;
            double v = (double)wo[(size_t)i * 9 + tap];
            bits |= (unsigned long long)(v > mean ? 1 : 0) << b;
        }
        wb[tid] = bits;
        pw[(size_t)o * 36 + tid] = bits;
    }
    __syncthreads();
    if (tid < 9) {
        int pc = __popcll(wb[tid * 4]) + __popcll(wb[tid * 4 + 1]) +
                 __popcll(wb[tid * 4 + 2]) + __popcll(wb[tid * 4 + 3]);
        Tg[o * 9 + tid] = 256 - 2 * pc;
    }
    if (tid == 0) scaleg[o] = scale;
}

// ---------------- kernel 3: popcount conv ----------------
#define HT 16       // output rows per block
#define OT 8        // output channels per block
#define COLS 58     // W_ + 2 halo
#define SLOT 5      // u64 per (r,c): 4 data + 1 pad (breaks LDS bank stride)

__global__ __launch_bounds__(256) void conv_kernel(const unsigned long long* __restrict__ px,
                                                   const unsigned long long* __restrict__ pw,
                                                   const int* __restrict__ Tg,
                                                   const float* __restrict__ scaleg,
                                                   float* __restrict__ out) {
    __shared__ unsigned long long xt[(HT + 2) * COLS * SLOT];
    __shared__ unsigned long long wws[OT * 36];
    __shared__ int Ts[OT * 9];
    __shared__ float ss[OT];

    int tid = threadIdx.x;
    int h0 = blockIdx.x * HT;
    int og = blockIdx.y;
    int n  = blockIdx.z;

    // stage packed x tile (zero-padded halo)
    for (int p = tid; p < (HT + 2) * COLS; p += 256) {
        int r = p / COLS, c = p % COLS;
        int gh = h0 + r - 1, gw = c - 1;
        unsigned long long v0 = 0, v1 = 0, v2 = 0, v3 = 0;
        if ((unsigned)gh < H_ && (unsigned)gw < W_) {
            const unsigned long long* src = px + ((size_t)(n * H_ + gh) * W_ + gw) * PWORDS;
            v0 = src[0]; v1 = src[1]; v2 = src[2]; v3 = src[3];
        }
        unsigned long long* dst = &xt[p * SLOT];
        dst[0] = v0; dst[1] = v1; dst[2] = v2; dst[3] = v3;
    }
    // stage weights / corrections / scales
    for (int p = tid; p < OT * 36; p += 256)
        wws[p] = pw[(size_t)(og * OT + p / 36) * 36 + (p % 36)];
    if (tid < OT * 9) Ts[tid] = Tg[(og * OT + tid / 9) * 9 + tid % 9];
    if (tid < OT) ss[tid] = scaleg[og * OT + tid];
    __syncthreads();

    if (tid >= 224) return;           // 16 rows x 14 w-tiles of 4
    int hl = tid / 14, wt = tid % 14;
    int w0 = wt * 4;

    int acc[OT][4];
#pragma unroll
    for (int o = 0; o < OT; ++o) {
        acc[o][0] = 0; acc[o][1] = 0; acc[o][2] = 0; acc[o][3] = 0;
    }

#pragma unroll
    for (int kh = 0; kh < 3; ++kh) {
        int r = hl + kh;
        const unsigned long long* xrow = &xt[((size_t)r * COLS + w0) * SLOT];
#pragma unroll
        for (int wp = 0; wp < 2; ++wp) {
            unsigned long long xr0[6], xr1[6];
#pragma unroll
            for (int j = 0; j < 6; ++j) {
                xr0[j] = xrow[j * SLOT + wp * 2];
                xr1[j] = xrow[j * SLOT + wp * 2 + 1];
            }
#pragma unroll
            for (int o = 0; o < OT; ++o) {
#pragma unroll
                for (int kw = 0; kw < 3; ++kw) {
                    const unsigned long long* wwp = &wws[o * 36 + (kh * 3 + kw) * 4 + wp * 2];
                    unsigned long long wa = wwp[0], wb2 = wwp[1];
#pragma unroll
                    for (int wi = 0; wi < 4; ++wi) {
                        acc[o][wi] = __popcll(xr0[kw + wi] ^ wa) + acc[o][wi];
                        acc[o][wi] = __popcll(xr1[kw + wi] ^ wb2) + acc[o][wi];
                    }
                }
            }
        }
    }

    int h = h0 + hl;
    if (h >= H_) return;              // phantom rows in last h-tile

    int corr[OT][4];
#pragma unroll
    for (int o = 0; o < OT; ++o) {
        corr[o][0] = 0; corr[o][1] = 0; corr[o][2] = 0; corr[o][3] = 0;
    }
    bool border = (h == 0) | (h == H_ - 1) | (wt == 0) | (wt == 13);
    if (border) {
        for (int kh = 0; kh < 3; ++kh) {
            int ih = h + kh - 1;
            bool rowInv = (ih < 0) | (ih >= H_);
            for (int kw = 0; kw < 3; ++kw) {
                for (int wi = 0; wi < 4; ++wi) {
                    int iw = w0 + wi + kw - 1;
                    bool colInv = (iw < 0) | (iw >= W_);
                    if (rowInv | colInv) {
#pragma unroll
                        for (int o = 0; o < OT; ++o)
                            corr[o][wi] += Ts[o * 9 + kh * 3 + kw];
                    }
                }
            }
        }
    }

    size_t obase = ((size_t)(n * C_ + og * OT) * H_ + h) * W_ + w0;
#pragma unroll
    for (int o = 0; o < OT; ++o) {
        float s = ss[o];
        float4 v;
        v.x = s * (float)(2304 - 2 * acc[o][0] - corr[o][0]);
        v.y = s * (float)(2304 - 2 * acc[o][1] - corr[o][1]);
        v.z = s * (float)(2304 - 2 * acc[o][2] - corr[o][2]);
        v.w = s * (float)(2304 - 2 * acc[o][3] - corr[o][3]);
        *(float4*)(out + obase + (size_t)o * (H_ * W_)) = v;
    }
}

extern "C" void kernel_launch(void* const* d_in, const int* in_sizes, int n_in,
                              void* d_out, int out_size, void* d_ws, size_t ws_size,
                              hipStream_t stream) {
    const float* x   = (const float*)d_in[0];
    const float* wgt = (const float*)d_in[1];
    float* out = (float*)d_out;
    char* ws = (char*)d_ws;

    unsigned long long* px = (unsigned long long*)ws;
    unsigned long long* pw = (unsigned long long*)(ws + PWB_OFF);
    int*   Tg = (int*)(ws + T_OFF);
    float* sg = (float*)(ws + S_OFF);

    // 32*4*56*56 / 256 = 1568 blocks
    pack_x_kernel<<<dim3(1568), dim3(256), 0, stream>>>(x, px);
    pack_w_kernel<<<dim3(256), dim3(256), 0, stream>>>(wgt, pw, Tg, sg);
    conv_kernel<<<dim3(4, 32, 32), dim3(256), 0, stream>>>(px, pw, Tg, sg, out);
}

// Round 2
// 375.626 us; speedup vs baseline: 1.9714x; 1.9714x over previous
//
#include <hip/hip_runtime.h>
#include <cstdint>
#include <cstddef>

#define N_ 32
#define C_ 256
#define H_ 56
#define W_ 56
#define PWORDS 4   // 256 channels / 64 bits

// workspace layout (bytes)
static constexpr size_t PX_ELEMS = (size_t)N_ * PWORDS * H_ * W_;     // 401408 u64
static constexpr size_t PX_BYTES = PX_ELEMS * 8;                      // 3,211,264
static constexpr size_t PWB_OFF  = PX_BYTES;
static constexpr size_t PW_ELEMS = (size_t)C_ * 9 * PWORDS;           // 9216 u64
static constexpr size_t T_OFF    = PWB_OFF + PW_ELEMS * 8;
static constexpr size_t S_OFF    = T_OFF + (size_t)C_ * 9 * 4;

// ---------------- kernel 1: pack sign bits of x ----------------
// px layout: [n][word][h][w]  (word = group of 64 input channels)
// each thread packs 4 consecutive w positions via float4 loads
__global__ __launch_bounds__(256) void pack_x_kernel(const float* __restrict__ x,
                                                     unsigned long long* __restrict__ px) {
    int idx = blockIdx.x * 256 + threadIdx.x;   // 32*4*56*14 = 100352 threads
    int w4 = idx % 14;
    int t  = idx / 14;
    int h  = t % H_;
    int t2 = t / H_;
    int word = t2 & 3;
    int n    = t2 >> 2;
    const float* xp = x + ((size_t)(n * C_ + word * 64)) * (H_ * W_) + h * W_ + w4 * 4;
    unsigned long long m0 = 0, m1 = 0, m2 = 0, m3 = 0;
#pragma unroll 8
    for (int b = 0; b < 64; ++b) {
        float4 v = *(const float4*)(xp + (size_t)b * (H_ * W_));
        m0 |= (unsigned long long)(v.x > 0.0f) << b;
        m1 |= (unsigned long long)(v.y > 0.0f) << b;
        m2 |= (unsigned long long)(v.z > 0.0f) << b;
        m3 |= (unsigned long long)(v.w > 0.0f) << b;
    }
    unsigned long long* dst = px + (((size_t)n * PWORDS + word) * H_ + h) * W_ + w4 * 4;
    dst[0] = m0; dst[1] = m1; dst[2] = m2; dst[3] = m3;
}

// ---------------- kernel 2: binarize weights ----------------
// pw layout: [o][tap][word], tap = kh*3+kw; Tg[o][tap] = 256 - 2*popc256(bits)
__global__ __launch_bounds__(256) void pack_w_kernel(const float* __restrict__ wt,
                                                     unsigned long long* __restrict__ pw,
                                                     int* __restrict__ Tg,
                                                     float* __restrict__ scaleg) {
    __shared__ double red[256];
    __shared__ unsigned long long wb[36];
    int o = blockIdx.x, tid = threadIdx.x;
    const float* wo = wt + (size_t)o * 2304;

    double s = 0;
    for (int j = tid; j < 2304; j += 256) s += (double)wo[j];
    red[tid] = s;
    __syncthreads();
    for (int k = 128; k > 0; k >>= 1) {
        if (tid < k) red[tid] += red[tid + k];
        __syncthreads();
    }
    double mean = red[0] / 2304.0;
    __syncthreads();

    double s2 = 0;
    for (int j = tid; j < 2304; j += 256) s2 += fabs((double)wo[j] - mean);
    red[tid] = s2;
    __syncthreads();
    for (int k = 128; k > 0; k >>= 1) {
        if (tid < k) red[tid] += red[tid + k];
        __syncthreads();
    }
    float scale = (float)(red[0] / 2304.0);

    if (tid < 36) {
        int tap = tid >> 2, word = tid & 3;
        unsigned long long bits = 0;
        for (int b = 0; b < 64; ++b) {
            int i = word * 64 + b;
            double v = (double)wo[(size_t)i * 9 + tap];
            bits |= (unsigned long long)(v > mean ? 1 : 0) << b;
        }
        wb[tid] = bits;
        pw[(size_t)o * 36 + tid] = bits;
    }
    __syncthreads();
    if (tid < 9) {
        int pc = __popcll(wb[tid * 4]) + __popcll(wb[tid * 4 + 1]) +
                 __popcll(wb[tid * 4 + 2]) + __popcll(wb[tid * 4 + 3]);
        Tg[o * 9 + tid] = 256 - 2 * pc;
    }
    if (tid == 0) scaleg[o] = scale;
}

// ---------------- kernel 3: popcount conv ----------------
#define HT 16        // output rows per block
#define OT 4         // output channels per block
#define ROWS 18      // HT + 2 halo
#define COLSP 58     // W_ + 2 halo; [word][row][col] planes, b128-aligned, conflict-free

__global__ __launch_bounds__(256, 4) void conv_kernel(const unsigned long long* __restrict__ px,
                                                      const unsigned long long* __restrict__ pw,
                                                      const int* __restrict__ Tg,
                                                      const float* __restrict__ scaleg,
                                                      float* __restrict__ out) {
    __shared__ unsigned long long xt[PWORDS * ROWS * COLSP];  // 33408 B
    __shared__ unsigned long long wws[OT * 36];
    __shared__ int Ts[OT * 9];
    __shared__ float ss[OT];

    int tid = threadIdx.x;
    int h0 = blockIdx.x * HT;
    int og = blockIdx.y;
    int n  = blockIdx.z;

    // stage packed x planes (zero-padded halo); contiguous c => coalesced
    for (int i = tid; i < PWORDS * ROWS * COLSP; i += 256) {
        int word = i / (ROWS * COLSP);
        int rem  = i - word * (ROWS * COLSP);
        int r = rem / COLSP;
        int c = rem - r * COLSP;
        int gh = h0 + r - 1, gw = c - 1;
        unsigned long long v = 0;
        if ((unsigned)gh < H_ && (unsigned)gw < W_)
            v = px[(((size_t)n * PWORDS + word) * H_ + gh) * W_ + gw];
        xt[i] = v;
    }
    if (tid < OT * 36) wws[tid] = pw[(size_t)(og * OT + tid / 36) * 36 + (tid % 36)];
    if (tid < OT * 9)  Ts[tid]  = Tg[(og * OT + tid / 9) * 9 + tid % 9];
    if (tid < OT)      ss[tid]  = scaleg[og * OT + tid];
    __syncthreads();

    int hl  = tid >> 4;          // 0..15
    int wtl = tid & 15;          // 0..15; only 0..13 store
    int w0  = (wtl < 14 ? wtl : 13) * 4;   // even -> b128-aligned LDS reads
    int h   = h0 + hl;

    int acc[OT][4];
#pragma unroll
    for (int o = 0; o < OT; ++o) {
        acc[o][0] = 0; acc[o][1] = 0; acc[o][2] = 0; acc[o][3] = 0;
    }

    // dynamic kh/word loops (small I$, low regs); static o/kw/wi
    for (int kh = 0; kh < 3; ++kh) {
        int r = hl + kh;
        for (int word = 0; word < PWORDS; ++word) {
            const unsigned long long* row = &xt[(word * ROWS + r) * COLSP + w0];
            ulonglong2 p0 = *(const ulonglong2*)(row);
            ulonglong2 p1 = *(const ulonglong2*)(row + 2);
            ulonglong2 p2 = *(const ulonglong2*)(row + 4);
            unsigned long long xr0 = p0.x, xr1 = p0.y, xr2 = p1.x,
                               xr3 = p1.y, xr4 = p2.x, xr5 = p2.y;
#pragma unroll
            for (int o = 0; o < OT; ++o) {
                const unsigned long long* wp = &wws[o * 36 + (kh * 3) * 4 + word];
                unsigned long long wv0 = wp[0], wv1 = wp[4], wv2 = wp[8];
                acc[o][0] += __popcll(xr0 ^ wv0);
                acc[o][1] += __popcll(xr1 ^ wv0);
                acc[o][2] += __popcll(xr2 ^ wv0);
                acc[o][3] += __popcll(xr3 ^ wv0);
                acc[o][0] += __popcll(xr1 ^ wv1);
                acc[o][1] += __popcll(xr2 ^ wv1);
                acc[o][2] += __popcll(xr3 ^ wv1);
                acc[o][3] += __popcll(xr4 ^ wv1);
                acc[o][0] += __popcll(xr2 ^ wv2);
                acc[o][1] += __popcll(xr3 ^ wv2);
                acc[o][2] += __popcll(xr4 ^ wv2);
                acc[o][3] += __popcll(xr5 ^ wv2);
            }
        }
    }

    if (wtl >= 14 || h >= H_) return;

    // 9-bit invalid-tap masks per output column (border only)
    int inv0 = 0, inv1 = 0, inv2 = 0, inv3 = 0;
    bool border = (h == 0) | (h == H_ - 1) | (w0 == 0) | (w0 == 52);
    if (border) {
        for (int kh = 0; kh < 3; ++kh) {
            int ih = h + kh - 1;
            bool rI = (unsigned)ih >= H_;
            for (int kw = 0; kw < 3; ++kw) {
                int bit = 1 << (kh * 3 + kw);
                int iw = w0 + kw - 1;
                if (rI | ((unsigned)(iw + 0) >= W_)) inv0 |= bit;
                if (rI | ((unsigned)(iw + 1) >= W_)) inv1 |= bit;
                if (rI | ((unsigned)(iw + 2) >= W_)) inv2 |= bit;
                if (rI | ((unsigned)(iw + 3) >= W_)) inv3 |= bit;
            }
        }
    }

    size_t obase = ((size_t)(n * C_ + og * OT) * H_ + h) * W_ + w0;
#pragma unroll
    for (int o = 0; o < OT; ++o) {
        float s = ss[o];
        int c0 = 0, c1 = 0, c2 = 0, c3 = 0;
        if (inv0 | inv1 | inv2 | inv3) {
            for (int t = 0; t < 9; ++t) {
                int tv = Ts[o * 9 + t];
                if ((inv0 >> t) & 1) c0 += tv;
                if ((inv1 >> t) & 1) c1 += tv;
                if ((inv2 >> t) & 1) c2 += tv;
                if ((inv3 >> t) & 1) c3 += tv;
            }
        }
        float4 v;
        v.x = s * (float)(2304 - 2 * acc[o][0] - c0);
        v.y = s * (float)(2304 - 2 * acc[o][1] - c1);
        v.z = s * (float)(2304 - 2 * acc[o][2] - c2);
        v.w = s * (float)(2304 - 2 * acc[o][3] - c3);
        *(float4*)(out + obase + (size_t)o * (H_ * W_)) = v;
    }
}

extern "C" void kernel_launch(void* const* d_in, const int* in_sizes, int n_in,
                              void* d_out, int out_size, void* d_ws, size_t ws_size,
                              hipStream_t stream) {
    const float* x   = (const float*)d_in[0];
    const float* wgt = (const float*)d_in[1];
    float* out = (float*)d_out;
    char* ws = (char*)d_ws;

    unsigned long long* px = (unsigned long long*)ws;
    unsigned long long* pw = (unsigned long long*)(ws + PWB_OFF);
    int*   Tg = (int*)(ws + T_OFF);
    float* sg = (float*)(ws + S_OFF);

    pack_x_kernel<<<dim3(392), dim3(256), 0, stream>>>(x, px);
    pack_w_kernel<<<dim3(256), dim3(256), 0, stream>>>(wgt, pw, Tg, sg);
    conv_kernel<<<dim3(4, C_ / OT, N_), dim3(256), 0, stream>>>(px, pw, Tg, sg, out);
}